// Round 10
// baseline (354.196 us; speedup 1.0000x reference)
//
#include <hip/hip_runtime.h>
#include <math.h>

// Problem constants (B, CIN, CGD, CE, G, H, W) = (4, 256, 256, 64, 4, 80, 80)
#define NB    4
#define CINC  256
#define NG    4
#define NPIX  6400          // H*W
#define NROWS 132           // 64 embed + 64 guide_embed + 4 conf
#define CHG   65            // tree-filter channels per group (64 + norm)
#define TEPS  1e-8f
#define TP    128           // gemm position tile
#define KC    32            // gemm K chunk
#define SCH   5             // sweep channels per block (13 chunks * 5 = 65)
#define SPITCH 6416         // LDS pitch: %32==16 (clean banks), %4==0 (b128 ok)
#define SWT   320           // sweep threads: 5 waves, wave w owns channel w
#define LSC   512           // level-start LDS cache entries

typedef unsigned short u16;
typedef unsigned int   u32;

// ---------------------------------------------------------------------------
// Fused GEMM + prep. Blocks 0..199: GEMM (b = bid/50, tile = bid%50).
// Blocks 200..203: per-batch tree prep on otherwise-idle CUs (204 <= 256 CUs
// so prep's serial pointer-doubling hides completely under the GEMM).
// prep uses PACKED (anc<<16 | lvl) u32 state: 1 gather + 1 write per node
// per round, early-exit when all ancestors reach the root.
// ---------------------------------------------------------------------------
__global__ __launch_bounds__(256) void gemm_prep_kernel(
    const float* __restrict__ f, const float* __restrict__ g,
    const float* __restrict__ We, const float* __restrict__ Wc,
    const float* __restrict__ Wg, float* __restrict__ emb,
    const int* __restrict__ order, const int* __restrict__ parent,
    u16* __restrict__ par16, int* __restrict__ ls,
    int* __restrict__ nl, int* __restrict__ inv)
{
  __shared__ __align__(16) char smem[50176];   // gemm: 3 tiles; prep: pk[]
  __shared__ int smax;
  const int bid = blockIdx.x;
  const int tid = threadIdx.x;

  if (bid < 200) {
    // ================= GEMM role =================
    const int b  = bid / 50;
    const int t0 = (bid - b*50) * TP;
    const int i = tid >> 4;   // 0..15 rowgroup (rows 8i..8i+7)
    const int j = tid & 15;   // 0..15 posgroup

    float (*fT)[TP]   = reinterpret_cast<float(*)[TP]>(smem);            // 16 KB
    float (*gT)[TP]   = reinterpret_cast<float(*)[TP]>(smem + 16384);    // 16 KB
    float (*wTt)[136] = reinterpret_cast<float(*)[136]>(smem + 32768);   // 17.4 KB

    float acc[8][8];
    #pragma unroll
    for (int r = 0; r < 8; ++r)
      #pragma unroll
      for (int p = 0; p < 8; ++p) acc[r][p] = 0.f;
    float accc[8];
    #pragma unroll
    for (int p = 0; p < 8; ++p) accc[p] = 0.f;

    const float* fb = f + (size_t)b*CINC*NPIX;
    const float* gb = g + (size_t)b*CINC*NPIX;

    for (int kc = 0; kc < CINC; kc += KC) {
      { // stage x tiles: 32x128 each; 16 contiguous floats per thread
        int kk = tid >> 3;
        int p  = (tid & 7) * 16;
        const float4* srcf = reinterpret_cast<const float4*>(fb + (size_t)(kc+kk)*NPIX + t0 + p);
        const float4* srcg = reinterpret_cast<const float4*>(gb + (size_t)(kc+kk)*NPIX + t0 + p);
        float4* df = reinterpret_cast<float4*>(&fT[kk][p]);
        float4* dg = reinterpret_cast<float4*>(&gT[kk][p]);
        #pragma unroll
        for (int q = 0; q < 4; ++q) { df[q] = srcf[q]; dg[q] = srcg[q]; }
      }
      // stage weights transposed: wTt[kb][r]
      for (int s = tid; s < 528; s += 256) {
        int r = s >> 2, kb0 = (s & 3) * 8;
        const float* wsrc;
        if (r < 64)       wsrc = We + r*CINC + kc + kb0;
        else if (r < 128) wsrc = Wg + (r-64)*CINC + kc + kb0;
        else              wsrc = Wc + (r-128)*CINC + kc + kb0;
        const float4* wv = reinterpret_cast<const float4*>(wsrc);
        float4 v0 = wv[0], v1 = wv[1];
        wTt[kb0+0][r]=v0.x; wTt[kb0+1][r]=v0.y; wTt[kb0+2][r]=v0.z; wTt[kb0+3][r]=v0.w;
        wTt[kb0+4][r]=v1.x; wTt[kb0+5][r]=v1.y; wTt[kb0+6][r]=v1.z; wTt[kb0+7][r]=v1.w;
      }
      __syncthreads();

      const float (*xT)[TP] = (i < 8) ? fT : gT;
      for (int kk = 0; kk < KC; ++kk) {
        float4 x0 = *reinterpret_cast<const float4*>(&xT[kk][4*j]);
        float4 x1 = *reinterpret_cast<const float4*>(&xT[kk][64 + 4*j]);
        float4 w0 = *reinterpret_cast<const float4*>(&wTt[kk][8*i]);
        float4 w1 = *reinterpret_cast<const float4*>(&wTt[kk][8*i + 4]);
#define FMA8(r, wv) \
        acc[r][0] += (wv)*x0.x; acc[r][1] += (wv)*x0.y; acc[r][2] += (wv)*x0.z; acc[r][3] += (wv)*x0.w; \
        acc[r][4] += (wv)*x1.x; acc[r][5] += (wv)*x1.y; acc[r][6] += (wv)*x1.z; acc[r][7] += (wv)*x1.w;
        FMA8(0, w0.x) FMA8(1, w0.y) FMA8(2, w0.z) FMA8(3, w0.w)
        FMA8(4, w1.x) FMA8(5, w1.y) FMA8(6, w1.z) FMA8(7, w1.w)
#undef FMA8
        if (i < 4) {
          float wcf = wTt[kk][128 + i];
          accc[0] += wcf*x0.x; accc[1] += wcf*x0.y; accc[2] += wcf*x0.z; accc[3] += wcf*x0.w;
          accc[4] += wcf*x1.x; accc[5] += wcf*x1.y; accc[6] += wcf*x1.z; accc[7] += wcf*x1.w;
        }
      }
      __syncthreads();
    }

    float* eb = emb + (size_t)b*NPIX*NROWS;
    #pragma unroll
    for (int p = 0; p < 8; ++p) {
      int n = t0 + ((p >> 2) * 64) + 4*j + (p & 3);
      float4 v0 = make_float4(acc[0][p], acc[1][p], acc[2][p], acc[3][p]);
      float4 v1 = make_float4(acc[4][p], acc[5][p], acc[6][p], acc[7][p]);
      float* base = eb + (size_t)n*NROWS + 8*i;
      *reinterpret_cast<float4*>(base)     = v0;
      *reinterpret_cast<float4*>(base + 4) = v1;
      if (i < 4) eb[(size_t)n*NROWS + 128 + i] = 1.f / (1.f + expf(-accc[p]));
    }
  } else {
    // ================= prep role (one block per batch) =================
    const int b = bid - 200;
    const int* par = parent + b*NPIX;
    const int* ord = order + b*NPIX;
    u32* pk = reinterpret_cast<u32*>(smem);    // packed (anc<<16)|lvl, 25.6 KB

    #pragma unroll
    for (int it = 0; it < NPIX/256; ++it) {
      int k = tid + it*256;
      int p = par[k];
      pk[k] = ((u32)p << 16) | (k == 0 ? 0u : 1u);
      inv[b*NPIX + ord[k]] = k;
      par16[b*NPIX + k] = (u16)p;
    }
    __syncthreads();

    // pointer doubling on packed state; early-exit on convergence
    for (int r = 0; r < 13; ++r) {
      u32 nv[NPIX/256];
      int done = 1;
      #pragma unroll
      for (int it = 0; it < NPIX/256; ++it) {
        int k = tid + it*256;
        u32 w = pk[k];
        u32 a = w >> 16;
        done &= (a == 0u);
        u32 pw = pk[a];
        nv[it] = (pw & 0xffff0000u) | ((w + pw) & 0xffffu);  // anc=anc[a], lvl+=lvl[a]
      }
      if (__syncthreads_and(done)) break;
      #pragma unroll
      for (int it = 0; it < NPIX/256; ++it) pk[tid + it*256] = nv[it];
      __syncthreads();
    }

    if (tid == 0) smax = 0;
    __syncthreads();
    int m = 0;
    #pragma unroll
    for (int it = 0; it < NPIX/256; ++it) m = max(m, (int)(pk[tid + it*256] & 0xffffu));
    atomicMax(&smax, m);
    __syncthreads();
    if (tid == 0) {
      nl[b] = smax + 1;
      ls[b*(NPIX+2) + smax + 1] = NPIX;
    }
    #pragma unroll
    for (int it = 0; it < NPIX/256; ++it) {
      int k = tid + it*256;
      int lv = (int)(pk[k] & 0xffffu);
      if (k == 0 || lv != (int)(pk[k-1] & 0xffffu)) ls[b*(NPIX+2) + lv] = k;
    }
  }
}

// ---------------------------------------------------------------------------
// Fused wdist + gatherX (both consume only emb + static inputs).
// Blocks 0..99: edge weights wq[b][g][k] (u16 quantized, transposed).
// Blocks 100..899: gatherX — aggT[bg][c][k] = f[g*64+c][ord[k]]*conf_g[ord[k]].
// ---------------------------------------------------------------------------
__global__ __launch_bounds__(256) void wgx_kernel(
    const float* __restrict__ emb, const int* __restrict__ order,
    const int* __restrict__ parent, const float* __restrict__ beta,
    const float* __restrict__ f, u16* __restrict__ wq,
    float* __restrict__ aggT)
{
  const int bid = blockIdx.x;
  const int tid = threadIdx.x;
  __shared__ int   s_ord[128];
  __shared__ float s_cf[128];

  if (bid < 100) {
    // ---------------- wdist role ----------------
    int idx = bid*256 + tid;   // b*NPIX + k
    int b = idx / NPIX;
    int k = idx - b*NPIX;
    int n  = order[idx];
    int kp = parent[idx];
    int np = order[b*NPIX + kp];
    const float4* e0 = reinterpret_cast<const float4*>(emb + ((size_t)b*NPIX + n )*NROWS);
    const float4* e1 = reinterpret_cast<const float4*>(emb + ((size_t)b*NPIX + np)*NROWS);
    float d[NG] = {0.f, 0.f, 0.f, 0.f};
    #pragma unroll
    for (int q = 0; q < 32; ++q) {            // channels 0..127
      float4 a = e0[q], c = e1[q];
      int gg = (q & 15) >> 2;                 // group = (channel%64)/16
      float t0 = a.x-c.x, t1 = a.y-c.y, t2 = a.z-c.z, t3 = a.w-c.w;
      d[gg] += t0*t0 + t1*t1 + t2*t2 + t3*t3;
    }
    #pragma unroll
    for (int gg = 0; gg < NG; ++gg) {
      float bg = beta[gg];
      float w = expf(-(d[gg] + bg*bg));
      wq[((size_t)(b*NG+gg))*NPIX + k] = (u16)(w*65535.f + 0.5f);
    }
  } else {
    // ---------------- gatherX role ----------------
    const int r = bid - 100;             // tile*16 + pair
    const int pair = r & 15, tile = r >> 4;
    const int b = pair >> 2, g = pair & 3;
    const int k0 = tile * 128;

    if (tid < 128) {
      int n = order[b*NPIX + k0 + tid];
      s_ord[tid] = n;
      s_cf[tid]  = emb[((size_t)b*NPIX + n)*NROWS + 128 + g];
    }
    __syncthreads();

    const float* fb = f + (size_t)b*CINC*NPIX + (size_t)g*64*NPIX;
    float* dst = aggT + (size_t)(b*NG+g)*CHG*NPIX + k0;
    const int c0 = tid >> 7;             // 0..1
    const int j  = tid & 127;
    const int n  = s_ord[j];
    const float cf = s_cf[j];
    #pragma unroll 4
    for (int cc = c0; cc < 64; cc += 2) {
      dst[(size_t)cc*NPIX + j] = fb[(size_t)cc*NPIX + n] * cf;
    }
    if (tid < 128) dst[(size_t)64*NPIX + j] = cf;
  }
}

// ---------------------------------------------------------------------------
// Tree filter, LDS-resident. Block = (b, g, 5-channel chunk), 320 threads =
// 5 waves; wave w owns channel w exclusively. In-order DS pipe => zero
// hardware waits in the serial chain; compiler-only fences pin level order.
// R10: per-step DS ops cut 4 -> 3 per wave by packing (w<<16|p) into one
// u32 s_pw (single ds_read_b32); staging/writeback use aligned float4 LDS
// ops (SPITCH 6416: %32==16 clean banks, 16B-aligned).
// ---------------------------------------------------------------------------
__global__ __launch_bounds__(SWT, 1) void sweep_kernel(
    float* __restrict__ aggT, const u16* __restrict__ wq,
    const u16* __restrict__ par16, const int* __restrict__ ls,
    const int* __restrict__ nl)
{
  extern __shared__ char smem[];
  float* s_agg = (float*)smem;                         // 5*6416*4 = 128,320 B
  u32*  s_pw   = (u32*)(smem + 128320);                // 25,600 B: (w<<16)|p
  int*  s_ls   = (int*)(smem + 128320 + 25600);        // 2,048 B

  const int bid = blockIdx.x;
  const int b = bid / (NG*13);
  const int r = bid - b*(NG*13);
  const int g = r / 13;
  const int ch0 = (r - g*13) * SCH;
  const int tid = threadIdx.x;
  const int ld = tid & 63;
  const int cw = tid >> 6;          // wave id == owned channel (0..4)
  const int bg = b*NG + g;

  // ---- stage: each wave loads its own channel plane (coalesced float4) ----
  {
    const float4* src = reinterpret_cast<const float4*>(aggT + ((size_t)bg*CHG + ch0 + cw)*NPIX);
    float4* dst = reinterpret_cast<float4*>(s_agg + cw*SPITCH);
    for (int i = ld; i < NPIX/4; i += 64) dst[i] = src[i];
  }
  {
    const u32* wsrc = reinterpret_cast<const u32*>(wq + (size_t)bg*NPIX);
    const u32* psrc = reinterpret_cast<const u32*>(par16 + (size_t)b*NPIX);
    uint2* dpw = reinterpret_cast<uint2*>(s_pw);
    for (int i = tid; i < NPIX/2; i += SWT) {
      u32 ww = wsrc[i];        // two w16 (lo = node 2i, hi = node 2i+1)
      u32 pp = psrc[i];        // two p16
      uint2 v;
      v.x = ((ww & 0xffffu) << 16) | (pp & 0xffffu);
      v.y = (ww & 0xffff0000u)     | (pp >> 16);
      dpw[i] = v;
    }
  }
  const int* lsb = ls + b*(NPIX+2);
  const int L = nl[b];
  for (int i = tid; i <= L && i < LSC; i += SWT) s_ls[i] = lsb[i];
  __syncthreads();

  const float qs = 1.0f/65535.0f;
  float* sa = s_agg + cw*SPITCH;      // this wave's private channel plane
  auto LS = [&](int x) -> int { x = min(x, L); return (x < LSC) ? s_ls[x] : lsb[x]; };

  // ---- UP: children (level lev+1) scatter-add into parents. Per-wave. ----
  {
    int lev = L-2;
    int A = LS(lev), Bv = LS(lev+1), Cv = LS(lev+2);
    while (lev >= 0) {
      int nxt = (lev > 0) ? LS(lev-1) : 0;
      for (int k = Bv + ld; k < Cv; k += 64) {
        u32 pw = s_pw[k];
        float wv = (float)(pw >> 16) * qs;
        atomicAdd(&sa[pw & 0xffffu], wv * sa[k]);
      }
      asm volatile("" ::: "memory");   // compiler-only: pin level order
      Cv = Bv; Bv = A; A = nxt; --lev;
    }
  }

  // ---- DOWN (in place): out[k] = a + w*(out[p] - w*a). Per-wave. ----
  {
    int lev = 1;
    int A = LS(1), Bv = LS(2);
    while (lev < L) {
      int nxt = LS(lev+2);             // clamped; garbage value never used
      for (int k = A + ld; k < Bv; k += 64) {
        u32 pw = s_pw[k];
        float wv = (float)(pw >> 16) * qs;
        float a  = sa[k];
        float op = sa[pw & 0xffffu];
        sa[k] = fmaf(wv, op - wv*a, a);
      }
      asm volatile("" ::: "memory");   // compiler-only: pin level order
      A = Bv; Bv = nxt; ++lev;
    }
  }

  __syncthreads();

  // ---- writeback IN PLACE to aggT (coalesced float4, per-wave channel) ----
  {
    float4* dst = reinterpret_cast<float4*>(aggT + ((size_t)bg*CHG + ch0 + cw)*NPIX);
    const float4* srcp = reinterpret_cast<const float4*>(s_agg + cw*SPITCH);
    for (int i = ld; i < NPIX/4; i += 64) dst[i] = srcp[i];
  }
}

// ---------------------------------------------------------------------------
// Epilogue (n-major): out[ch][n] = gamma*filt[ch][inv[n]]/(eps+norm) + f[ch][n]
// f/out coalesced; aggT SoA rows gathered (25.6 KB each, L2-absorbed).
// ---------------------------------------------------------------------------
__global__ __launch_bounds__(256) void epilogue_kernel(
    const float* __restrict__ aggT, const int* __restrict__ inv,
    const float* __restrict__ f, const float* __restrict__ gamma,
    float* __restrict__ out)
{
  const int bid = blockIdx.x;          // tile*NB + b
  const int b = bid & 3, tile = bid >> 2;
  const int n0 = tile * 64;
  const int tid = threadIdx.x;
  const int g = tid >> 6, j = tid & 63;

  __shared__ int s_k[64];
  if (tid < 64) s_k[tid] = inv[b*NPIX + n0 + tid];
  __syncthreads();

  const int k = s_k[j];
  const float* at = aggT + (size_t)(b*NG + g)*CHG*NPIX;
  const float rn = 1.f / (TEPS + at[(size_t)64*NPIX + k]);
  const float gam = gamma[0];
  const float* fb = f   + (size_t)b*CINC*NPIX + (size_t)g*64*NPIX;
  float*       ob = out + (size_t)b*CINC*NPIX + (size_t)g*64*NPIX;
  #pragma unroll 4
  for (int cc = 0; cc < 64; ++cc) {
    float val = at[(size_t)cc*NPIX + k];
    float fv  = fb[(size_t)cc*NPIX + n0 + j];
    ob[(size_t)cc*NPIX + n0 + j] = fmaf(gam, val*rn, fv);
  }
}

// ---------------------------------------------------------------------------
extern "C" void kernel_launch(void* const* d_in, const int* in_sizes, int n_in,
                              void* d_out, int out_size, void* d_ws, size_t ws_size,
                              hipStream_t stream)
{
  const float* f     = (const float*)d_in[0];
  const float* g     = (const float*)d_in[1];
  const float* We    = (const float*)d_in[2];
  const float* Wc    = (const float*)d_in[3];
  const float* Wg    = (const float*)d_in[4];
  const float* beta  = (const float*)d_in[5];
  const float* gamma = (const float*)d_in[6];
  const int* order   = (const int*)d_in[7];
  const int* parent  = (const int*)d_in[8];
  float* out = (float*)d_out;

  char* ws = (char*)d_ws;
  size_t off = 0;
  auto carve = [&](size_t bytes) -> void* {
    void* p = ws + off;
    off = (off + bytes + 255) & ~(size_t)255;
    return p;
  };
  float* emb = (float*)carve((size_t)NB*NPIX*NROWS*4);     // 13.5 MB
  float* aggT= (float*)carve((size_t)NB*NG*CHG*NPIX*4);    // 26.6 MB (in/out of sweep)
  u16*  wq   = (u16*) carve((size_t)NB*NG*NPIX*2);         // 0.2 MB
  u16*  par16= (u16*) carve((size_t)NB*NPIX*2);
  int*  ls   = (int*) carve((size_t)NB*(NPIX+2)*4);
  int*  nl   = (int*) carve((size_t)NB*4);
  int*  inv  = (int*) carve((size_t)NB*NPIX*4);

  const int sweep_lds = 128320 + 25600 + 2048;             // 155,968 B
  hipFuncSetAttribute((const void*)sweep_kernel,
                      hipFuncAttributeMaxDynamicSharedMemorySize, sweep_lds);

  hipLaunchKernelGGL(gemm_prep_kernel, dim3(204),          dim3(256), 0, stream,
                     f, g, We, Wc, Wg, emb, order, parent, par16, ls, nl, inv);
  hipLaunchKernelGGL(wgx_kernel,       dim3(900),          dim3(256), 0, stream,
                     emb, order, parent, beta, f, wq, aggT);
  hipLaunchKernelGGL(sweep_kernel,     dim3(NB*NG*13),     dim3(SWT), sweep_lds, stream,
                     aggT, wq, par16, ls, nl);
  hipLaunchKernelGGL(epilogue_kernel,  dim3((NPIX/64)*NB), dim3(256), 0, stream,
                     aggT, inv, f, gamma, out);
}

// Round 11
// 321.506 us; speedup vs baseline: 1.1017x; 1.1017x over previous
//
#include <hip/hip_runtime.h>
#include <math.h>

// Problem constants (B, CIN, CGD, CE, G, H, W) = (4, 256, 256, 64, 4, 80, 80)
#define NB    4
#define CINC  256
#define NG    4
#define NPIX  6400          // H*W
#define NROWS 132           // 64 embed + 64 guide_embed + 4 conf
#define CHG   65            // tree-filter channels per group (64 + norm)
#define TEPS  1e-8f
#define TP    128           // gemm position tile
#define KC    32            // gemm K chunk
#define SCH   4             // sweep data channels per block (16 chunks * 4 = 64)
#define SPITCH 6416         // LDS pitch: %32==16 (clean banks), %4==0 (b128 ok)
#define SWT   320           // sweep threads: 5 waves (4 data + 1 norm)
#define LSC   512           // level-start LDS cache entries

typedef unsigned short u16;
typedef unsigned int   u32;

// ---------------------------------------------------------------------------
// Fused GEMM + prep. Blocks 0..199: GEMM (b = bid/50, tile = bid%50).
// Blocks 200..203: per-batch tree prep on otherwise-idle CUs (204 <= 256 CUs
// so prep's serial pointer-doubling hides completely under the GEMM).
// prep uses PACKED (anc<<16 | lvl) u32 state; early-exit on convergence.
// ---------------------------------------------------------------------------
__global__ __launch_bounds__(256) void gemm_prep_kernel(
    const float* __restrict__ f, const float* __restrict__ g,
    const float* __restrict__ We, const float* __restrict__ Wc,
    const float* __restrict__ Wg, float* __restrict__ emb,
    const int* __restrict__ order, const int* __restrict__ parent,
    u16* __restrict__ par16, int* __restrict__ ls,
    int* __restrict__ nl, int* __restrict__ inv)
{
  __shared__ __align__(16) char smem[50176];   // gemm: 3 tiles; prep: pk[]
  __shared__ int smax;
  const int bid = blockIdx.x;
  const int tid = threadIdx.x;

  if (bid < 200) {
    // ================= GEMM role =================
    const int b  = bid / 50;
    const int t0 = (bid - b*50) * TP;
    const int i = tid >> 4;   // 0..15 rowgroup (rows 8i..8i+7)
    const int j = tid & 15;   // 0..15 posgroup

    float (*fT)[TP]   = reinterpret_cast<float(*)[TP]>(smem);            // 16 KB
    float (*gT)[TP]   = reinterpret_cast<float(*)[TP]>(smem + 16384);    // 16 KB
    float (*wTt)[136] = reinterpret_cast<float(*)[136]>(smem + 32768);   // 17.4 KB

    float acc[8][8];
    #pragma unroll
    for (int r = 0; r < 8; ++r)
      #pragma unroll
      for (int p = 0; p < 8; ++p) acc[r][p] = 0.f;
    float accc[8];
    #pragma unroll
    for (int p = 0; p < 8; ++p) accc[p] = 0.f;

    const float* fb = f + (size_t)b*CINC*NPIX;
    const float* gb = g + (size_t)b*CINC*NPIX;

    for (int kc = 0; kc < CINC; kc += KC) {
      { // stage x tiles: 32x128 each; 16 contiguous floats per thread
        int kk = tid >> 3;
        int p  = (tid & 7) * 16;
        const float4* srcf = reinterpret_cast<const float4*>(fb + (size_t)(kc+kk)*NPIX + t0 + p);
        const float4* srcg = reinterpret_cast<const float4*>(gb + (size_t)(kc+kk)*NPIX + t0 + p);
        float4* df = reinterpret_cast<float4*>(&fT[kk][p]);
        float4* dg = reinterpret_cast<float4*>(&gT[kk][p]);
        #pragma unroll
        for (int q = 0; q < 4; ++q) { df[q] = srcf[q]; dg[q] = srcg[q]; }
      }
      // stage weights transposed: wTt[kb][r]
      for (int s = tid; s < 528; s += 256) {
        int r = s >> 2, kb0 = (s & 3) * 8;
        const float* wsrc;
        if (r < 64)       wsrc = We + r*CINC + kc + kb0;
        else if (r < 128) wsrc = Wg + (r-64)*CINC + kc + kb0;
        else              wsrc = Wc + (r-128)*CINC + kc + kb0;
        const float4* wv = reinterpret_cast<const float4*>(wsrc);
        float4 v0 = wv[0], v1 = wv[1];
        wTt[kb0+0][r]=v0.x; wTt[kb0+1][r]=v0.y; wTt[kb0+2][r]=v0.z; wTt[kb0+3][r]=v0.w;
        wTt[kb0+4][r]=v1.x; wTt[kb0+5][r]=v1.y; wTt[kb0+6][r]=v1.z; wTt[kb0+7][r]=v1.w;
      }
      __syncthreads();

      const float (*xT)[TP] = (i < 8) ? fT : gT;
      for (int kk = 0; kk < KC; ++kk) {
        float4 x0 = *reinterpret_cast<const float4*>(&xT[kk][4*j]);
        float4 x1 = *reinterpret_cast<const float4*>(&xT[kk][64 + 4*j]);
        float4 w0 = *reinterpret_cast<const float4*>(&wTt[kk][8*i]);
        float4 w1 = *reinterpret_cast<const float4*>(&wTt[kk][8*i + 4]);
#define FMA8(r, wv) \
        acc[r][0] += (wv)*x0.x; acc[r][1] += (wv)*x0.y; acc[r][2] += (wv)*x0.z; acc[r][3] += (wv)*x0.w; \
        acc[r][4] += (wv)*x1.x; acc[r][5] += (wv)*x1.y; acc[r][6] += (wv)*x1.z; acc[r][7] += (wv)*x1.w;
        FMA8(0, w0.x) FMA8(1, w0.y) FMA8(2, w0.z) FMA8(3, w0.w)
        FMA8(4, w1.x) FMA8(5, w1.y) FMA8(6, w1.z) FMA8(7, w1.w)
#undef FMA8
        if (i < 4) {
          float wcf = wTt[kk][128 + i];
          accc[0] += wcf*x0.x; accc[1] += wcf*x0.y; accc[2] += wcf*x0.z; accc[3] += wcf*x0.w;
          accc[4] += wcf*x1.x; accc[5] += wcf*x1.y; accc[6] += wcf*x1.z; accc[7] += wcf*x1.w;
        }
      }
      __syncthreads();
    }

    float* eb = emb + (size_t)b*NPIX*NROWS;
    #pragma unroll
    for (int p = 0; p < 8; ++p) {
      int n = t0 + ((p >> 2) * 64) + 4*j + (p & 3);
      float4 v0 = make_float4(acc[0][p], acc[1][p], acc[2][p], acc[3][p]);
      float4 v1 = make_float4(acc[4][p], acc[5][p], acc[6][p], acc[7][p]);
      float* base = eb + (size_t)n*NROWS + 8*i;
      *reinterpret_cast<float4*>(base)     = v0;
      *reinterpret_cast<float4*>(base + 4) = v1;
      if (i < 4) eb[(size_t)n*NROWS + 128 + i] = 1.f / (1.f + expf(-accc[p]));
    }
  } else {
    // ================= prep role (one block per batch) =================
    const int b = bid - 200;
    const int* par = parent + b*NPIX;
    const int* ord = order + b*NPIX;
    u32* pk = reinterpret_cast<u32*>(smem);    // packed (anc<<16)|lvl, 25.6 KB

    #pragma unroll
    for (int it = 0; it < NPIX/256; ++it) {
      int k = tid + it*256;
      int p = par[k];
      pk[k] = ((u32)p << 16) | (k == 0 ? 0u : 1u);
      inv[b*NPIX + ord[k]] = k;
      par16[b*NPIX + k] = (u16)p;
    }
    __syncthreads();

    // pointer doubling on packed state; early-exit on convergence
    for (int r = 0; r < 13; ++r) {
      u32 nv[NPIX/256];
      int done = 1;
      #pragma unroll
      for (int it = 0; it < NPIX/256; ++it) {
        int k = tid + it*256;
        u32 w = pk[k];
        u32 a = w >> 16;
        done &= (a == 0u);
        u32 pw = pk[a];
        nv[it] = (pw & 0xffff0000u) | ((w + pw) & 0xffffu);  // anc=anc[a], lvl+=lvl[a]
      }
      if (__syncthreads_and(done)) break;
      #pragma unroll
      for (int it = 0; it < NPIX/256; ++it) pk[tid + it*256] = nv[it];
      __syncthreads();
    }

    if (tid == 0) smax = 0;
    __syncthreads();
    int m = 0;
    #pragma unroll
    for (int it = 0; it < NPIX/256; ++it) m = max(m, (int)(pk[tid + it*256] & 0xffffu));
    atomicMax(&smax, m);
    __syncthreads();
    if (tid == 0) {
      nl[b] = smax + 1;
      ls[b*(NPIX+2) + smax + 1] = NPIX;
    }
    #pragma unroll
    for (int it = 0; it < NPIX/256; ++it) {
      int k = tid + it*256;
      int lv = (int)(pk[k] & 0xffffu);
      if (k == 0 || lv != (int)(pk[k-1] & 0xffffu)) ls[b*(NPIX+2) + lv] = k;
    }
  }
}

// ---------------------------------------------------------------------------
// Fused wdist + gatherX (both consume only emb + static inputs).
// Blocks 0..99: edge weights wq[b][g][k] (u16 quantized, transposed).
// Blocks 100..899: gatherX — aggT[bg][c][k] = f[g*64+c][ord[k]]*conf_g[ord[k]].
// ---------------------------------------------------------------------------
__global__ __launch_bounds__(256) void wgx_kernel(
    const float* __restrict__ emb, const int* __restrict__ order,
    const int* __restrict__ parent, const float* __restrict__ beta,
    const float* __restrict__ f, u16* __restrict__ wq,
    float* __restrict__ aggT)
{
  const int bid = blockIdx.x;
  const int tid = threadIdx.x;
  __shared__ int   s_ord[128];
  __shared__ float s_cf[128];

  if (bid < 100) {
    // ---------------- wdist role ----------------
    int idx = bid*256 + tid;   // b*NPIX + k
    int b = idx / NPIX;
    int k = idx - b*NPIX;
    int n  = order[idx];
    int kp = parent[idx];
    int np = order[b*NPIX + kp];
    const float4* e0 = reinterpret_cast<const float4*>(emb + ((size_t)b*NPIX + n )*NROWS);
    const float4* e1 = reinterpret_cast<const float4*>(emb + ((size_t)b*NPIX + np)*NROWS);
    float d[NG] = {0.f, 0.f, 0.f, 0.f};
    #pragma unroll
    for (int q = 0; q < 32; ++q) {            // channels 0..127
      float4 a = e0[q], c = e1[q];
      int gg = (q & 15) >> 2;                 // group = (channel%64)/16
      float t0 = a.x-c.x, t1 = a.y-c.y, t2 = a.z-c.z, t3 = a.w-c.w;
      d[gg] += t0*t0 + t1*t1 + t2*t2 + t3*t3;
    }
    #pragma unroll
    for (int gg = 0; gg < NG; ++gg) {
      float bg = beta[gg];
      float w = expf(-(d[gg] + bg*bg));
      wq[((size_t)(b*NG+gg))*NPIX + k] = (u16)(w*65535.f + 0.5f);
    }
  } else {
    // ---------------- gatherX role ----------------
    const int r = bid - 100;             // tile*16 + pair
    const int pair = r & 15, tile = r >> 4;
    const int b = pair >> 2, g = pair & 3;
    const int k0 = tile * 128;

    if (tid < 128) {
      int n = order[b*NPIX + k0 + tid];
      s_ord[tid] = n;
      s_cf[tid]  = emb[((size_t)b*NPIX + n)*NROWS + 128 + g];
    }
    __syncthreads();

    const float* fb = f + (size_t)b*CINC*NPIX + (size_t)g*64*NPIX;
    float* dst = aggT + (size_t)(b*NG+g)*CHG*NPIX + k0;
    const int c0 = tid >> 7;             // 0..1
    const int j  = tid & 127;
    const int n  = s_ord[j];
    const float cf = s_cf[j];
    #pragma unroll 4
    for (int cc = c0; cc < 64; cc += 2) {
      dst[(size_t)cc*NPIX + j] = fb[(size_t)cc*NPIX + n] * cf;
    }
    if (tid < 128) dst[(size_t)64*NPIX + j] = cf;
  }
}

// ---------------------------------------------------------------------------
// Tree filter + fused epilogue, LDS-resident. Block = (b, g, 4-channel
// chunk), 320 threads = 5 waves. Waves 0-3 own data channels ch0..ch0+3;
// WAVE 4 redundantly sweeps the NORM channel (ch 64) — same chain length,
// runs concurrently, so every block can normalize locally. 256 blocks =
// 1/CU. In-order DS pipe => zero hardware waits in the chain (R5/R6/R10-
// validated floor). After the chain, the block writes out[] DIRECTLY:
//   out[ch][n] = gamma * s_agg[c][inv[n]] / (eps + s_agg[4][inv[n]]) + f[ch][n]
// (inv/f/out coalesced; value lookups are LDS gathers). This deletes the
// epilogue kernel, its launch gap, the 26.6 MB aggT writeback and the
// epilogue's gather-amplified aggT re-read.
// ---------------------------------------------------------------------------
__global__ __launch_bounds__(SWT, 1) void sweep_kernel(
    const float* __restrict__ aggT, const u16* __restrict__ wq,
    const u16* __restrict__ par16, const int* __restrict__ ls,
    const int* __restrict__ nl, const int* __restrict__ inv,
    const float* __restrict__ f, const float* __restrict__ gamma,
    float* __restrict__ out)
{
  extern __shared__ char smem[];
  float* s_agg = (float*)smem;                         // 5*6416*4 = 128,320 B
  u32*  s_pw   = (u32*)(smem + 128320);                // 25,600 B: (w<<16)|p
  int*  s_ls   = (int*)(smem + 128320 + 25600);        // 2,048 B

  const int bid = blockIdx.x;
  const int b = bid / (NG*16);
  const int r = bid - b*(NG*16);
  const int g = r / 16;
  const int ch0 = (r - g*16) * SCH;
  const int tid = threadIdx.x;
  const int ld = tid & 63;
  const int cw = tid >> 6;          // wave id: 0..3 = data channels, 4 = norm
  const int bg = b*NG + g;

  // ---- stage: each wave loads its plane (coalesced float4) ----
  {
    const int pc = (cw < 4) ? (ch0 + cw) : 64;     // plane channel
    const float4* src = reinterpret_cast<const float4*>(aggT + ((size_t)bg*CHG + pc)*NPIX);
    float4* dst = reinterpret_cast<float4*>(s_agg + cw*SPITCH);
    for (int i = ld; i < NPIX/4; i += 64) dst[i] = src[i];
  }
  {
    const u32* wsrc = reinterpret_cast<const u32*>(wq + (size_t)bg*NPIX);
    const u32* psrc = reinterpret_cast<const u32*>(par16 + (size_t)b*NPIX);
    uint2* dpw = reinterpret_cast<uint2*>(s_pw);
    for (int i = tid; i < NPIX/2; i += SWT) {
      u32 ww = wsrc[i];        // two w16 (lo = node 2i, hi = node 2i+1)
      u32 pp = psrc[i];        // two p16
      uint2 v;
      v.x = ((ww & 0xffffu) << 16) | (pp & 0xffffu);
      v.y = (ww & 0xffff0000u)     | (pp >> 16);
      dpw[i] = v;
    }
  }
  const int* lsb = ls + b*(NPIX+2);
  const int L = nl[b];
  for (int i = tid; i <= L && i < LSC; i += SWT) s_ls[i] = lsb[i];
  __syncthreads();

  const float qs = 1.0f/65535.0f;
  float* sa = s_agg + cw*SPITCH;      // this wave's private plane
  auto LS = [&](int x) -> int { x = min(x, L); return (x < LSC) ? s_ls[x] : lsb[x]; };

  // ---- UP: children (level lev+1) scatter-add into parents. Per-wave. ----
  {
    int lev = L-2;
    int A = LS(lev), Bv = LS(lev+1), Cv = LS(lev+2);
    while (lev >= 0) {
      int nxt = (lev > 0) ? LS(lev-1) : 0;
      for (int k = Bv + ld; k < Cv; k += 64) {
        u32 pw = s_pw[k];
        float wv = (float)(pw >> 16) * qs;
        atomicAdd(&sa[pw & 0xffffu], wv * sa[k]);
      }
      asm volatile("" ::: "memory");   // compiler-only: pin level order
      Cv = Bv; Bv = A; A = nxt; --lev;
    }
  }

  // ---- DOWN (in place): out[k] = a + w*(out[p] - w*a). Per-wave. ----
  {
    int lev = 1;
    int A = LS(1), Bv = LS(2);
    while (lev < L) {
      int nxt = LS(lev+2);             // clamped; garbage value never used
      for (int k = A + ld; k < Bv; k += 64) {
        u32 pw = s_pw[k];
        float wv = (float)(pw >> 16) * qs;
        float a  = sa[k];
        float op = sa[pw & 0xffffu];
        sa[k] = fmaf(wv, op - wv*a, a);
      }
      asm volatile("" ::: "memory");   // compiler-only: pin level order
      A = Bv; Bv = nxt; ++lev;
    }
  }

  __syncthreads();

  // ---- fused epilogue: direct out write (n-major, coalesced) ----
  {
    const float gam = gamma[0];
    const int* invb = inv + b*NPIX;
    const float* fch = f   + (size_t)b*CINC*NPIX + (size_t)(g*64 + ch0)*NPIX;
    float*       och = out + (size_t)b*CINC*NPIX + (size_t)(g*64 + ch0)*NPIX;
    const float* s_nrm = s_agg + 4*SPITCH;
    for (int n = tid; n < NPIX; n += SWT) {
      int k = invb[n];
      float rn = 1.f / (TEPS + s_nrm[k]);
      #pragma unroll
      for (int c = 0; c < SCH; ++c) {
        float val = s_agg[c*SPITCH + k];
        och[(size_t)c*NPIX + n] = fmaf(gam, val*rn, fch[(size_t)c*NPIX + n]);
      }
    }
  }
}

// ---------------------------------------------------------------------------
extern "C" void kernel_launch(void* const* d_in, const int* in_sizes, int n_in,
                              void* d_out, int out_size, void* d_ws, size_t ws_size,
                              hipStream_t stream)
{
  const float* f     = (const float*)d_in[0];
  const float* g     = (const float*)d_in[1];
  const float* We    = (const float*)d_in[2];
  const float* Wc    = (const float*)d_in[3];
  const float* Wg    = (const float*)d_in[4];
  const float* beta  = (const float*)d_in[5];
  const float* gamma = (const float*)d_in[6];
  const int* order   = (const int*)d_in[7];
  const int* parent  = (const int*)d_in[8];
  float* out = (float*)d_out;

  char* ws = (char*)d_ws;
  size_t off = 0;
  auto carve = [&](size_t bytes) -> void* {
    void* p = ws + off;
    off = (off + bytes + 255) & ~(size_t)255;
    return p;
  };
  float* emb = (float*)carve((size_t)NB*NPIX*NROWS*4);     // 13.5 MB
  float* aggT= (float*)carve((size_t)NB*NG*CHG*NPIX*4);    // 26.6 MB (gatherX -> sweep)
  u16*  wq   = (u16*) carve((size_t)NB*NG*NPIX*2);         // 0.2 MB
  u16*  par16= (u16*) carve((size_t)NB*NPIX*2);
  int*  ls   = (int*) carve((size_t)NB*(NPIX+2)*4);
  int*  nl   = (int*) carve((size_t)NB*4);
  int*  inv  = (int*) carve((size_t)NB*NPIX*4);

  const int sweep_lds = 128320 + 25600 + 2048;             // 155,968 B
  hipFuncSetAttribute((const void*)sweep_kernel,
                      hipFuncAttributeMaxDynamicSharedMemorySize, sweep_lds);

  hipLaunchKernelGGL(gemm_prep_kernel, dim3(204),          dim3(256), 0, stream,
                     f, g, We, Wc, Wg, emb, order, parent, par16, ls, nl, inv);
  hipLaunchKernelGGL(wgx_kernel,       dim3(900),          dim3(256), 0, stream,
                     emb, order, parent, beta, f, wq, aggT);
  hipLaunchKernelGGL(sweep_kernel,     dim3(NB*NG*16),     dim3(SWT), sweep_lds, stream,
                     aggT, wq, par16, ls, nl, inv, f, gamma, out);
}